// Round 5
// baseline (376.642 us; speedup 1.0000x reference)
//
#include <hip/hip_runtime.h>
#include <hip/hip_bf16.h>
#include <stdint.h>

#define DFEAT 256
#define NPTS  8192

typedef __attribute__((ext_vector_type(8)))  short bf16x8;   // 8 bf16 = 4 VGPRs
typedef __attribute__((ext_vector_type(16))) float f32x16;   // 32x32 C/D
typedef __attribute__((ext_vector_type(4)))  int   int4v;
typedef __attribute__((ext_vector_type(4)))  float f32x4;

#define AS1 __attribute__((address_space(1)))
#define AS3 __attribute__((address_space(3)))

__device__ inline void dma16(const void* g, void* l) {
  // async global->LDS, 16B/lane; LDS dest = wave-uniform base + lane*16
  __builtin_amdgcn_global_load_lds((const AS1 uint32_t*)g, (AS3 uint32_t*)l, 16, 0, 0);
}

__device__ inline uint16_t f2bf(float f) {  // RNE fp32->bf16
  union { float f; uint32_t u; } v; v.f = f;
  return (uint16_t)((v.u + 0x7FFFu + ((v.u >> 16) & 1u)) >> 16);
}

// lgkmcnt(0)-only barrier: makes Ps writes visible WITHOUT draining vmcnt,
// so the in-flight DMA(t+1) keeps flying through the PV phase.
// simm16 = vmcnt[3:0] | expcnt<<4 | lgkmcnt<<8 | vmcnt[5:4]<<14 = 0xC07F.
__device__ inline void barrier_lgkm_only() {
  __asm__ __volatile__("" ::: "memory");
  __builtin_amdgcn_s_waitcnt(0xC07F);
  __builtin_amdgcn_s_barrier();
  __asm__ __volatile__("" ::: "memory");
}

// ---------------------------------------------------------------------------
// ws fragment layouts (written by ms_combine):
//  xaf: per 32-point block nb, chunk s=2*ks+g, lane 0..31:
//       X[d = s*8 .. +8][pt = nb*32+lane]  (A/B-frag order, k=d)
//       byte addr = nb*16384 + s*512 + lane*16.     (4 MB)
//  xbf: per 32-d block db, chunk u (n/8), lane:
//       X[d = db*32+lane][n = u*8 .. +8]   (PV A-frag order, k=n)
//       byte addr = db*524288 + u*512 + lane*16.    (4 MB)
// xaf's n-tile slice [j*32768, +32768) is DMA'd to LDS as an IDENTITY copy.
// ---------------------------------------------------------------------------

// Fused mean-shift step. Per WG: m-tile 64, 32 consecutive n-tiles of 64.
// XCD swizzle: all blocks on one XCD share q -> per-iter unique global data
// is 64KB per XCD (same xaf slice + same xbf slice) -> L2-resident reuse.
__global__ __launch_bounds__(256, 2) void ms_fused(
    const uint16_t* __restrict__ xaf,
    const uint16_t* __restrict__ xbf,
    float* __restrict__ num,           // [256][8192] fp32, pre-zeroed
    float* __restrict__ cs)            // [8192] fp32, pre-zeroed
{
  __shared__ __attribute__((aligned(16))) uint16_t XT[2][16384];  // 2x32KB stage
  __shared__ __attribute__((aligned(16))) uint16_t Ps[64 * 72];   // 144B rows

  const int tid  = threadIdx.x;
  const int w    = tid >> 6;
  const int lane = tid & 63;
  const int l31  = lane & 31;
  const int g    = lane >> 5;
  const int bid  = blockIdx.x;
  const int xcd  = bid & 7;                  // blockIdx%8 ~ XCD (heuristic)
  const int q    = xcd >> 1;                 // n-split shared per XCD
  const int mt   = (bid >> 3) + ((xcd & 1) << 6);
  const int m0   = mt * 64;
  const int a_sub = w >> 1;                  // S n-sub (0/1)
  const int b_sub = w & 1;                   // S m-sub (0/1)

  const char* xafc = (const char*)xaf;
  const char* xbfc = (const char*)xbf;
  char*       Psc  = (char*)Ps;

  // Xm B-fragments resident (64 VGPRs), one-time coalesced load
  bf16x8 Bm[16];
  {
    const char* bp = xafc + (size_t)(m0 / 32 + b_sub) * 16384 + g * 512 + l31 * 16;
    #pragma unroll
    for (int ks = 0; ks < 16; ++ks)
      Bm[ks] = __builtin_bit_cast(bf16x8, *(const int4v*)(bp + ks * 1024));
  }

  f32x16 accO[2][2];
  #pragma unroll
  for (int i = 0; i < 2; ++i)
    #pragma unroll
    for (int j = 0; j < 2; ++j)
      #pragma unroll
      for (int r = 0; r < 16; ++r) accO[i][j][r] = 0.0f;
  float csacc = 0.0f;

  const int mloc = 32 * b_sub + l31;
  const int kw   = (mloc ^ (mloc >> 3)) & 7;     // Ps write key
  const int j0   = q * 32;                        // first n-tile index

  // prologue: stage tile j0 into buf 0 (identity copy, 8x 16B per thread)
  {
    const char* src = xafc + (size_t)j0 * 32768;
    #pragma unroll
    for (int r = 0; r < 8; ++r)
      dma16(src + tid * 16 + r * 4096, (char*)XT[0] + tid * 16 + r * 4096);
  }

  for (int t = 0; t < 32; ++t) {
    const int jt  = j0 + t;
    const int cur = t & 1;
    __syncthreads();  // A: full drain — DMA(t) landed in XT[cur]; Ps writable

    // prefetch PV A-frags FIRST (so their vmcnt-wait doesn't drain the DMA)
    const int n0 = jt * 64;
    bf16x8 Xf[2][4];
    #pragma unroll
    for (int t2 = 0; t2 < 2; ++t2) {
      const char* xp = xbfc + (size_t)(2 * w + t2) * 524288 +
                       (size_t)(n0 >> 3) * 512 + g * 512 + l31 * 16;
      #pragma unroll
      for (int ks = 0; ks < 4; ++ks)
        Xf[t2][ks] = __builtin_bit_cast(bf16x8, *(const int4v*)(xp + ks * 1024));
    }
    __asm__ __volatile__("" ::: "memory");  // keep Xf issued before DMA

    // issue DMA(t+1) AFTER Xf -> it is the last vmem, drained only at A(t+1)
    if (t < 31) {
      const char* src = xafc + (size_t)(jt + 1) * 32768;
      #pragma unroll
      for (int r = 0; r < 8; ++r)
        dma16(src + tid * 16 + r * 4096,
              (char*)XT[cur ^ 1] + tid * 16 + r * 4096);
    }

    // ---- S = Xn^T Xm : A-frags from staged LDS; dual chains for ILP ----
    f32x16 s0, s1;
    #pragma unroll
    for (int r = 0; r < 16; ++r) { s0[r] = 0.0f; s1[r] = 0.0f; }
    {
      const char* ap = (const char*)XT[cur] + a_sub * 16384 + g * 512 + l31 * 16;
      #pragma unroll
      for (int ks2 = 0; ks2 < 8; ++ks2) {
        bf16x8 A0 = __builtin_bit_cast(bf16x8, *(const int4v*)(ap + (2*ks2) * 1024));
        bf16x8 A1 = __builtin_bit_cast(bf16x8, *(const int4v*)(ap + (2*ks2+1) * 1024));
        s0 = __builtin_amdgcn_mfma_f32_32x32x16_bf16(A0, Bm[2*ks2],   s0, 0, 0, 0);
        s1 = __builtin_amdgcn_mfma_f32_32x32x16_bf16(A1, Bm[2*ks2+1], s1, 0, 0, 0);
      }
    }

    // ---- P = exp(6S); colsum; pack to Ps (4 ds_write_b64, keyed rows) ----
    #pragma unroll
    for (int k = 0; k < 4; ++k) {
      float e0 = __expf(6.0f * (s0[4*k+0] + s1[4*k+0]));
      float e1 = __expf(6.0f * (s0[4*k+1] + s1[4*k+1]));
      float e2 = __expf(6.0f * (s0[4*k+2] + s1[4*k+2]));
      float e3 = __expf(6.0f * (s0[4*k+3] + s1[4*k+3]));
      csacc += (e0 + e1) + (e2 + e3);
      uint32_t lo = (uint32_t)f2bf(e0) | ((uint32_t)f2bf(e1) << 16);
      uint32_t hi = (uint32_t)f2bf(e2) | ((uint32_t)f2bf(e3) << 16);
      int p = (4 * a_sub + k) ^ kw;
      *(uint64_t*)(Psc + mloc * 144 + p * 16 + 8 * g) =
          ((uint64_t)hi << 32) | lo;
    }
    barrier_lgkm_only();  // B: Ps visible; DMA(t+1) keeps flying

    // ---- O[d,m] += Xn * P ----
    #pragma unroll
    for (int ks = 0; ks < 4; ++ks) {
      bf16x8 Bp[2];
      #pragma unroll
      for (int mm = 0; mm < 2; ++mm) {
        int mrow = 32 * mm + l31;
        int p = (2 * ks + g) ^ ((mrow ^ (mrow >> 3)) & 7);
        Bp[mm] = __builtin_bit_cast(bf16x8,
            *(const int4v*)(Psc + mrow * 144 + p * 16));
      }
      #pragma unroll
      for (int t2 = 0; t2 < 2; ++t2) {
        accO[t2][0] = __builtin_amdgcn_mfma_f32_32x32x16_bf16(Xf[t2][ks], Bp[0], accO[t2][0], 0,0,0);
        accO[t2][1] = __builtin_amdgcn_mfma_f32_32x32x16_bf16(Xf[t2][ks], Bp[1], accO[t2][1], 0,0,0);
      }
    }
  }

  // ---- epilogue: merge partials ----
  csacc += __shfl_xor(csacc, 32, 64);
  if (g == 0) atomicAdd(&cs[m0 + mloc], csacc);
  #pragma unroll
  for (int t2 = 0; t2 < 2; ++t2)
    #pragma unroll
    for (int mm = 0; mm < 2; ++mm)
      #pragma unroll
      for (int r = 0; r < 16; ++r) {
        int drow = 32 * (2 * w + t2) + (r & 3) + 8 * (r >> 2) + 4 * g;
        int mg   = m0 + 32 * mm + l31;
        atomicAdd(&num[(size_t)drow * NPTS + mg], accO[t2][mm][r]);
      }
}

// ---------------------------------------------------------------------------
// Combine. mode1: v = num/cs -> yout; zero num after read; zero cs_next.
//          mode0: v = src (initial fp32 X). Both: emit xaf + xbf frags.
// ---------------------------------------------------------------------------
__global__ __launch_bounds__(256) void ms_combine(
    const float* __restrict__ src, const float* __restrict__ csr,
    float* __restrict__ csz, float* __restrict__ yout,
    float* __restrict__ numz,
    uint16_t* __restrict__ xaf, uint16_t* __restrict__ xbf,
    const int mode)
{
  __shared__ uint16_t T[64][66];
  const int tid = threadIdx.x;
  const int n0 = blockIdx.x * 64;
  const int d0 = blockIdx.y * 64;

  #pragma unroll
  for (int i = 0; i < 4; ++i) {
    int e  = tid + i * 256;              // float4 slot
    int dl = e >> 4, nq = e & 15;
    size_t idx = (size_t)(d0 + dl) * NPTS + (n0 + nq * 4);
    f32x4 v = *(const f32x4*)(src + idx);
    if (mode) {
      f32x4 c = *(const f32x4*)(csr + n0 + nq * 4);
      v /= c;
      *(f32x4*)(yout + idx) = v;
      f32x4 z = {0.f, 0.f, 0.f, 0.f};
      *(f32x4*)(numz + idx) = z;
    }
    #pragma unroll
    for (int k = 0; k < 4; ++k) T[dl][nq * 4 + k] = f2bf(v[k]);
  }
  if (mode && blockIdx.y == 0 && tid < 64) csz[n0 + tid] = 0.0f;
  __syncthreads();

  char* xafc = (char*)xaf;
  char* xbfc = (char*)xbf;
  // xaf chunks: (nb, s, lane) -> T[s*8 + j][nb*32+lane]
  #pragma unroll
  for (int i = 0; i < 2; ++i) {
    int c  = tid + i * 256;
    int nb = c >> 8, s2 = (c >> 5) & 7, ln = c & 31;
    union { uint32_t u[4]; int4v v; } pk;
    #pragma unroll
    for (int k = 0; k < 4; ++k) {
      uint32_t lo = T[s2 * 8 + 2 * k][nb * 32 + ln];
      uint32_t hi = T[s2 * 8 + 2 * k + 1][nb * 32 + ln];
      pk.u[k] = lo | (hi << 16);
    }
    *(int4v*)(xafc + (size_t)(n0 / 32 + nb) * 16384 +
              (size_t)(d0 / 8 + s2) * 512 + ln * 16) = pk.v;
  }
  // xbf chunks: (db, u, lane) -> T[db*32+lane][u*8 + j]  (row-contiguous)
  #pragma unroll
  for (int i = 0; i < 2; ++i) {
    int c  = tid + i * 256;
    int db = c >> 8, uu = (c >> 5) & 7, ln = c & 31;
    const uint16_t* tr = &T[db * 32 + ln][uu * 8];
    union { uint32_t u[4]; int4v v; } pk;
    #pragma unroll
    for (int k = 0; k < 4; ++k)
      pk.u[k] = (uint32_t)tr[2 * k] | ((uint32_t)tr[2 * k + 1] << 16);
    *(int4v*)(xbfc + (size_t)(d0 / 32 + db) * 524288 +
              (size_t)(n0 / 8 + uu) * 512 + ln * 16) = pk.v;
  }
}

extern "C" void kernel_launch(void* const* d_in, const int* in_sizes, int n_in,
                              void* d_out, int out_size, void* d_ws, size_t ws_size,
                              hipStream_t stream)
{
  (void)in_sizes; (void)n_in; (void)out_size; (void)ws_size;
  const float* X = (const float*)d_in[0];
  float* out = (float*)d_out;
  char* ws = (char*)d_ws;
  // ws: [0,4M) xaf ; [4M,8M) xbf ; [8M,16M) num ; [16M,+32K) cs0 ; [+32K) cs1
  uint16_t* xaf = (uint16_t*)(ws);
  uint16_t* xbf = (uint16_t*)(ws + (4u << 20));
  float*    num = (float*)   (ws + (8u << 20));
  float*    cs0 = (float*)   (ws + (16u << 20));
  float*    cs1 = (float*)   (ws + (16u << 20) + 32768);

  // zero num + both cs buffers once per call (ws is re-poisoned each call)
  hipMemsetAsync(ws + (8u << 20), 0, (8u << 20) + 65536, stream);

  dim3 cgrid(NPTS / 64, DFEAT / 64);
  ms_combine<<<cgrid, 256, 0, stream>>>(X, nullptr, nullptr, nullptr, nullptr,
                                        xaf, xbf, 0);
  for (int it = 0; it < 3; ++it) {
    float* csA = (it & 1) ? cs1 : cs0;
    float* csB = (it & 1) ? cs0 : cs1;
    ms_fused<<<512, 256, 0, stream>>>(xaf, xbf, num, csA);
    ms_combine<<<cgrid, 256, 0, stream>>>(num, csA, csB,
                                          out + (size_t)it * DFEAT * NPTS,
                                          num, xaf, xbf, 1);
  }
}

// Round 6
// 376.278 us; speedup vs baseline: 1.0010x; 1.0010x over previous
//
#include <hip/hip_runtime.h>
#include <hip/hip_bf16.h>
#include <stdint.h>

#define DFEAT 256
#define NPTS  8192

typedef __attribute__((ext_vector_type(8)))  short bf16x8;   // 8 bf16 = 4 VGPRs
typedef __attribute__((ext_vector_type(16))) float f32x16;   // 32x32 C/D
typedef __attribute__((ext_vector_type(4)))  int   int4v;
typedef __attribute__((ext_vector_type(4)))  float f32x4;

__device__ inline uint16_t f2bf(float f) {  // RNE fp32->bf16
  union { float f; uint32_t u; } v; v.f = f;
  return (uint16_t)((v.u + 0x7FFFu + ((v.u >> 16) & 1u)) >> 16);
}

// lgkmcnt(0)-only barrier (no vmcnt drain). All global loads in the K-loop
// are per-wave register loads, so barriers only need LDS visibility.
// simm16 = vmcnt[3:0]=15 | expcnt=7<<4 | lgkmcnt=0<<8 | vmcnt[5:4]=3<<14.
__device__ inline void barrier_lgkm_only() {
  __asm__ __volatile__("" ::: "memory");
  __builtin_amdgcn_s_waitcnt(0xC07F);
  __builtin_amdgcn_s_barrier();
  __asm__ __volatile__("" ::: "memory");
}

// ---------------------------------------------------------------------------
// ws fragment layouts (written by ms_combine):
//  xaf: per 32-point block nb, chunk s=2*ks+g, lane 0..31:
//       X[d = s*8 .. +8][pt = nb*32+lane]  (A/B-frag order, k=d)
//       byte addr = nb*16384 + s*512 + lane*16.     (4 MB)
//  xbf: per 32-d block db, chunk u (n/8), lane:
//       X[d = db*32+lane][n = u*8 .. +8]   (PV A-frag order, k=n)
//       byte addr = db*524288 + u*512 + lane*16.    (4 MB)
// Every hot-loop wave load is 1KB contiguous.
// ---------------------------------------------------------------------------

// Fused mean-shift step. Per WG: m-tile 64, 32 consecutive n-tiles of 64.
//   S[n,m] = Xn^T Xm  (A global->reg, 16 loads in flight; B resident regs)
//   P = exp(6S) -> LDS Ps (odd-stride, conflict-free) ; CS[m] += colsum
//   O[d,m] += Xn P    (A global->reg from xbf; B from Ps)
// No global_load_lds, no vmcnt drains: both barriers are lgkm-only.
// XCD swizzle: all blocks on an XCD share q -> 64KB/iter unique, L2-hot.
__global__ __launch_bounds__(256, 2) void ms_fused(
    const uint16_t* __restrict__ xaf,
    const uint16_t* __restrict__ xbf,
    float* __restrict__ num,           // [256][8192] fp32, pre-zeroed
    float* __restrict__ cs)            // [8192] fp32, pre-zeroed
{
  // Ps[m][n-pair]: dword index m*33 + n/2 (33-dword rows -> odd stride,
  // bank = (m + c) % 32 is a lane-permutation for every access). 8448 B.
  __shared__ uint32_t Ps[64 * 33];

  const int tid  = threadIdx.x;
  const int w    = tid >> 6;
  const int lane = tid & 63;
  const int l31  = lane & 31;
  const int g    = lane >> 5;
  const int bid  = blockIdx.x;
  const int xcd  = bid & 7;                  // blockIdx%8 ~ XCD (heuristic)
  const int q    = xcd >> 1;                 // n-split shared per XCD
  const int mt   = (bid >> 3) + ((xcd & 1) << 6);
  const int m0   = mt * 64;
  const int a_sub = w >> 1;                  // S n-sub (0/1)
  const int b_sub = w & 1;                   // S m-sub (0/1)

  const char* xafc = (const char*)xaf;
  const char* xbfc = (const char*)xbf;

  // Xm B-fragments resident (64 VGPRs), one-time coalesced load
  bf16x8 Bm[16];
  {
    const char* bp = xafc + (size_t)(m0 / 32 + b_sub) * 16384 + g * 512 + l31 * 16;
    #pragma unroll
    for (int ks = 0; ks < 16; ++ks)
      Bm[ks] = __builtin_bit_cast(bf16x8, *(const int4v*)(bp + ks * 1024));
  }

  f32x16 accO[2][2];
  #pragma unroll
  for (int i = 0; i < 2; ++i)
    #pragma unroll
    for (int j = 0; j < 2; ++j)
      #pragma unroll
      for (int r = 0; r < 16; ++r) accO[i][j][r] = 0.0f;
  float csacc = 0.0f;

  const int mloc = 32 * b_sub + l31;
  const int j0   = q * 32;                   // first n-tile index

  for (int t = 0; t < 32; ++t) {
    const int jt = j0 + t;
    const int n0 = jt * 64;
    barrier_lgkm_only();  // A: PV(t-1) Ps reads done -> Ps writable

    // ---- S A-frags: global->reg, all 16 loads in flight ----
    bf16x8 Af[16];
    {
      const char* ap = xafc + (size_t)((n0 >> 5) + a_sub) * 16384 + g * 512 + l31 * 16;
      #pragma unroll
      for (int ks = 0; ks < 16; ++ks)
        Af[ks] = __builtin_bit_cast(bf16x8, *(const int4v*)(ap + ks * 1024));
    }

    // ---- S = Xn^T Xm (wave quadrant) ----
    f32x16 s;
    #pragma unroll
    for (int r = 0; r < 16; ++r) s[r] = 0.0f;
    #pragma unroll
    for (int ks = 0; ks < 16; ++ks)
      s = __builtin_amdgcn_mfma_f32_32x32x16_bf16(Af[ks], Bm[ks], s, 0, 0, 0);

    __asm__ __volatile__("" ::: "memory");  // keep Xf issue after S loads

    // ---- PV A-frags: global->reg (issued here; consumed after barrier B,
    //      latency covered by exp/pack below) ----
    bf16x8 Xf[2][4];
    #pragma unroll
    for (int t2 = 0; t2 < 2; ++t2) {
      const char* xp = xbfc + (size_t)(2 * w + t2) * 524288 +
                       (size_t)(n0 >> 3) * 512 + g * 512 + l31 * 16;
      #pragma unroll
      for (int ks = 0; ks < 4; ++ks)
        Xf[t2][ks] = __builtin_bit_cast(bf16x8, *(const int4v*)(xp + ks * 1024));
    }

    // ---- P = exp(6S); colsum; pack to Ps (8 b32, conflict-free) ----
    // reg r -> n = 32*a_sub + (r&3) + 8*(r>>2) + 4*g; pairs -> dword n/2.
    #pragma unroll
    for (int k = 0; k < 4; ++k) {
      float e0 = __expf(6.0f * s[4*k+0]);
      float e1 = __expf(6.0f * s[4*k+1]);
      float e2 = __expf(6.0f * s[4*k+2]);
      float e3 = __expf(6.0f * s[4*k+3]);
      csacc += (e0 + e1) + (e2 + e3);
      int base = mloc * 33 + 16 * a_sub + 4 * k + 2 * g;
      Ps[base]     = (uint32_t)f2bf(e0) | ((uint32_t)f2bf(e1) << 16);
      Ps[base + 1] = (uint32_t)f2bf(e2) | ((uint32_t)f2bf(e3) << 16);
    }
    barrier_lgkm_only();  // B: Ps visible

    // ---- O[d,m] += Xn * P ----
    #pragma unroll
    for (int ks = 0; ks < 4; ++ks) {
      bf16x8 Bp[2];
      #pragma unroll
      for (int mm = 0; mm < 2; ++mm) {
        int b = (32 * mm + l31) * 33 + (2 * ks + g) * 4;   // chunk s=2ks+g
        union { uint32_t u[4]; bf16x8 v; } tb;
        tb.u[0] = Ps[b];     tb.u[1] = Ps[b + 1];
        tb.u[2] = Ps[b + 2]; tb.u[3] = Ps[b + 3];
        Bp[mm] = tb.v;
      }
      #pragma unroll
      for (int t2 = 0; t2 < 2; ++t2) {
        accO[t2][0] = __builtin_amdgcn_mfma_f32_32x32x16_bf16(Xf[t2][ks], Bp[0], accO[t2][0], 0,0,0);
        accO[t2][1] = __builtin_amdgcn_mfma_f32_32x32x16_bf16(Xf[t2][ks], Bp[1], accO[t2][1], 0,0,0);
      }
    }
  }

  // ---- epilogue: merge partials ----
  csacc += __shfl_xor(csacc, 32, 64);
  if (g == 0) atomicAdd(&cs[m0 + mloc], csacc);
  #pragma unroll
  for (int t2 = 0; t2 < 2; ++t2)
    #pragma unroll
    for (int mm = 0; mm < 2; ++mm)
      #pragma unroll
      for (int r = 0; r < 16; ++r) {
        int drow = 32 * (2 * w + t2) + (r & 3) + 8 * (r >> 2) + 4 * g;
        int mg   = m0 + 32 * mm + l31;
        atomicAdd(&num[(size_t)drow * NPTS + mg], accO[t2][mm][r]);
      }
}

// ---------------------------------------------------------------------------
// Combine. mode1: v = num/cs -> yout; zero num after read; zero cs_next.
//          mode0: v = src (initial fp32 X). Both: emit xaf + xbf frags.
// ---------------------------------------------------------------------------
__global__ __launch_bounds__(256) void ms_combine(
    const float* __restrict__ src, const float* __restrict__ csr,
    float* __restrict__ csz, float* __restrict__ yout,
    float* __restrict__ numz,
    uint16_t* __restrict__ xaf, uint16_t* __restrict__ xbf,
    const int mode)
{
  __shared__ uint16_t T[64][66];
  const int tid = threadIdx.x;
  const int n0 = blockIdx.x * 64;
  const int d0 = blockIdx.y * 64;

  #pragma unroll
  for (int i = 0; i < 4; ++i) {
    int e  = tid + i * 256;              // float4 slot
    int dl = e >> 4, nq = e & 15;
    size_t idx = (size_t)(d0 + dl) * NPTS + (n0 + nq * 4);
    f32x4 v = *(const f32x4*)(src + idx);
    if (mode) {
      f32x4 c = *(const f32x4*)(csr + n0 + nq * 4);
      v /= c;
      *(f32x4*)(yout + idx) = v;
      f32x4 z = {0.f, 0.f, 0.f, 0.f};
      *(f32x4*)(numz + idx) = z;
    }
    #pragma unroll
    for (int k = 0; k < 4; ++k) T[dl][nq * 4 + k] = f2bf(v[k]);
  }
  if (mode && blockIdx.y == 0 && tid < 64) csz[n0 + tid] = 0.0f;
  __syncthreads();

  char* xafc = (char*)xaf;
  char* xbfc = (char*)xbf;
  // xaf chunks: (nb, s, lane) -> T[s*8 + j][nb*32+lane]
  #pragma unroll
  for (int i = 0; i < 2; ++i) {
    int c  = tid + i * 256;
    int nb = c >> 8, s2 = (c >> 5) & 7, ln = c & 31;
    union { uint32_t u[4]; int4v v; } pk;
    #pragma unroll
    for (int k = 0; k < 4; ++k) {
      uint32_t lo = T[s2 * 8 + 2 * k][nb * 32 + ln];
      uint32_t hi = T[s2 * 8 + 2 * k + 1][nb * 32 + ln];
      pk.u[k] = lo | (hi << 16);
    }
    *(int4v*)(xafc + (size_t)(n0 / 32 + nb) * 16384 +
              (size_t)(d0 / 8 + s2) * 512 + ln * 16) = pk.v;
  }
  // xbf chunks: (db, u, lane) -> T[db*32+lane][u*8 + j]  (row-contiguous)
  #pragma unroll
  for (int i = 0; i < 2; ++i) {
    int c  = tid + i * 256;
    int db = c >> 8, uu = (c >> 5) & 7, ln = c & 31;
    const uint16_t* tr = &T[db * 32 + ln][uu * 8];
    union { uint32_t u[4]; int4v v; } pk;
    #pragma unroll
    for (int k = 0; k < 4; ++k)
      pk.u[k] = (uint32_t)tr[2 * k] | ((uint32_t)tr[2 * k + 1] << 16);
    *(int4v*)(xbfc + (size_t)(d0 / 32 + db) * 524288 +
              (size_t)(n0 / 8 + uu) * 512 + ln * 16) = pk.v;
  }
}

extern "C" void kernel_launch(void* const* d_in, const int* in_sizes, int n_in,
                              void* d_out, int out_size, void* d_ws, size_t ws_size,
                              hipStream_t stream)
{
  (void)in_sizes; (void)n_in; (void)out_size; (void)ws_size;
  const float* X = (const float*)d_in[0];
  float* out = (float*)d_out;
  char* ws = (char*)d_ws;
  // ws: [0,4M) xaf ; [4M,8M) xbf ; [8M,16M) num ; [16M,+32K) cs0 ; [+32K) cs1
  uint16_t* xaf = (uint16_t*)(ws);
  uint16_t* xbf = (uint16_t*)(ws + (4u << 20));
  float*    num = (float*)   (ws + (8u << 20));
  float*    cs0 = (float*)   (ws + (16u << 20));
  float*    cs1 = (float*)   (ws + (16u << 20) + 32768);

  // zero num + both cs buffers once per call (ws is re-poisoned each call)
  hipMemsetAsync(ws + (8u << 20), 0, (8u << 20) + 65536, stream);

  dim3 cgrid(NPTS / 64, DFEAT / 64);
  ms_combine<<<cgrid, 256, 0, stream>>>(X, nullptr, nullptr, nullptr, nullptr,
                                        xaf, xbf, 0);
  for (int it = 0; it < 3; ++it) {
    float* csA = (it & 1) ? cs1 : cs0;
    float* csB = (it & 1) ? cs0 : cs1;
    ms_fused<<<512, 256, 0, stream>>>(xaf, xbf, num, csA);
    ms_combine<<<cgrid, 256, 0, stream>>>(num, csA, csB,
                                          out + (size_t)it * DFEAT * NPTS,
                                          num, xaf, xbf, 1);
  }
}